// Round 5
// baseline (357.610 us; speedup 1.0000x reference)
//
#include <hip/hip_runtime.h>
#include <hip/hip_bf16.h>

typedef __attribute__((ext_vector_type(8))) _Float16 h8v;
typedef __attribute__((ext_vector_type(4))) float f4v;

__device__ __forceinline__ ushort f16bits(float f) {
    _Float16 h = (_Float16)f;
    return __builtin_bit_cast(unsigned short, h);
}

// ---------------- gate: alpha = softmax(x @ gate_W + gate_b) ----------------
__global__ __launch_bounds__(256) void gate_kernel(
    const float* __restrict__ x, const float* __restrict__ gW,
    const float* __restrict__ gb, float* __restrict__ alpha)
{
    int lane = threadIdx.x & 63;
    int wave = threadIdx.x >> 6;
    int row = blockIdx.x * 4 + wave;
    float4 xv = *(const float4*)(x + (size_t)row * 256 + lane * 4);
    const float* xp = (const float*)&xv;
    float p[8];
#pragma unroll
    for (int k = 0; k < 8; ++k) p[k] = 0.f;
#pragma unroll
    for (int j = 0; j < 4; ++j) {
        float xs = xp[j];
        const float* wr = gW + (lane * 4 + j) * 8;
#pragma unroll
        for (int k = 0; k < 8; ++k) p[k] = fmaf(xs, wr[k], p[k]);
    }
#pragma unroll
    for (int off = 32; off > 0; off >>= 1) {
#pragma unroll
        for (int k = 0; k < 8; ++k) p[k] += __shfl_xor(p[k], off);
    }
    float m = -1e30f;
#pragma unroll
    for (int k = 0; k < 8; ++k) { p[k] += gb[k]; m = fmaxf(m, p[k]); }
    float s = 0.f;
#pragma unroll
    for (int k = 0; k < 8; ++k) { p[k] = expf(p[k] - m); s += p[k]; }
    if (lane < 8) alpha[(size_t)row * 8 + lane] = p[lane] / s;
}

// ---- weight prep: retile to [layer][e][kgroup][o][32k'] fp16 ----------
// One block per (mat m 0..39, kgroup g 0..7). Thread o handles one output
// column: reads 32 K-values (coalesced across lanes per k'), writes 64B
// contiguous. Fragment loads in the GEMM become lane-contiguous 4KB blocks.
__global__ __launch_bounds__(256) void prep_weights(
    const float* __restrict__ blockW, const float* __restrict__ outW,
    ushort* __restrict__ Wg)
{
    const int m = blockIdx.x >> 3;
    const int g = blockIdx.x & 7;
    const float* src = (m < 32) ? (blockW + (size_t)m * 65536)
                                : (outW + (size_t)(m - 32) * 65536);
    const int o = threadIdx.x;
    uint pk[16];
#pragma unroll
    for (int kp = 0; kp < 16; ++kp) {
        float f0 = src[(size_t)(g * 32 + 2 * kp) * 256 + o];
        float f1 = src[(size_t)(g * 32 + 2 * kp + 1) * 256 + o];
        pk[kp] = (uint)f16bits(f0) | ((uint)f16bits(f1) << 16);
    }
    size_t base = (size_t)(m >> 3) * 524288 + (size_t)((m & 7) * 8 + g) * 8192
                + (size_t)o * 32;
    *(uint4*)(Wg + base)      = make_uint4(pk[0],  pk[1],  pk[2],  pk[3]);
    *(uint4*)(Wg + base + 8)  = make_uint4(pk[4],  pk[5],  pk[6],  pk[7]);
    *(uint4*)(Wg + base + 16) = make_uint4(pk[8],  pk[9],  pk[10], pk[11]);
    *(uint4*)(Wg + base + 24) = make_uint4(pk[12], pk[13], pk[14], pk[15]);
}

// ------------- fused MoIE layer, barrier-free K-loop -----------------------
// BM=64, BN=256 (full width -> in-place safe), 256 thr (4 waves 1x4),
// wave tile 64x64. A tile (64x256 fp16) in LDS (shared by all waves),
// staged once + one __syncthreads. B fragments stream global->registers
// (perfectly coalesced via prep layout), double-buffered 2 steps ahead.
// No barriers in the loop: waves self-stagger, MFMA pipe stays fed.
template<bool RELU>
__global__ __launch_bounds__(256, 2) void moie_gemm(
    const float* __restrict__ Hin, float* __restrict__ Hout,
    const ushort* __restrict__ Wg,
    const float* __restrict__ bias, const float* __restrict__ alpha)
{
    __shared__ __align__(16) ushort Ah[64 * 256];     // 32 KB, swizzled

    const int tid  = threadIdx.x;
    const int lane = tid & 63;
    const int wid  = tid >> 6;
    const int m0   = blockIdx.x * 64;
    const int wcol0 = wid * 64;
    const int kgl = lane >> 4;   // 0..3
    const int fr  = lane & 15;

    // ---- alpha for frag scaling: rows im*16+fr, all 8 experts -> 32 regs ----
    float areg[4][8];
#pragma unroll
    for (int im = 0; im < 4; ++im) {
        const float4* ap = (const float4*)(alpha + (size_t)(m0 + im * 16 + fr) * 8);
        float4 a0 = ap[0], a1 = ap[1];
        areg[im][0] = a0.x; areg[im][1] = a0.y; areg[im][2] = a0.z; areg[im][3] = a0.w;
        areg[im][4] = a1.x; areg[im][5] = a1.y; areg[im][6] = a1.z; areg[im][7] = a1.w;
    }

    // ---- stage A tile: Hin[m0+r][k] -> fp16, swizzle kg ^= (row&7) ----
    {
        const int r0  = tid >> 6;         // 0..3
        const int kk  = (tid & 63) * 4;   // 0..252
        const int kg  = kk >> 3;
        const int klo = kk & 7;           // 0 or 4
#pragma unroll
        for (int p = 0; p < 16; ++p) {
            int row = p * 4 + r0;
            float4 v = *(const float4*)(Hin + (size_t)(m0 + row) * 256 + kk);
            uint2 pkv;
            pkv.x = (uint)f16bits(v.x) | ((uint)f16bits(v.y) << 16);
            pkv.y = (uint)f16bits(v.z) | ((uint)f16bits(v.w) << 16);
            *(uint2*)&Ah[row * 256 + (kg ^ (row & 7)) * 8 + klo] = pkv;
        }
    }
    __syncthreads();   // A tile visible; ONLY barrier in the kernel

    // ---- B fragment pointers: tile phys = e*8+ki, 8192 ushorts each ----
    // lane byte offset within a frag-block: (fr*4 + kgl)*16 bytes
    const ushort* Wslice = Wg + (size_t)wcol0 * 32 + (size_t)(fr * 4 + kgl) * 8;

    f4v acc[4][4];
#pragma unroll
    for (int a = 0; a < 4; ++a)
#pragma unroll
        for (int b = 0; b < 4; ++b) acc[a][b] = (f4v){0.f, 0.f, 0.f, 0.f};

    // ---- prologue: prefetch steps s=0 (e=0,ki=0 -> phys 0) and s=1 (e=1 -> phys 8)
    h8v bfs[2][4];
#pragma unroll
    for (int in = 0; in < 4; ++in) {
        bfs[0][in] = *(const h8v*)(Wslice + (size_t)0 * 8192 + in * 512);
        bfs[1][in] = *(const h8v*)(Wslice + (size_t)8 * 8192 + in * 512);
    }

    h8v afc[4];   // cached A frags for current ki

#pragma unroll 1
    for (int ki = 0; ki < 8; ++ki) {
        // refresh A frags for this K-group (LDS, shared, read-only)
        const int kg0 = ki * 4;
#pragma unroll
        for (int im = 0; im < 4; ++im) {
            int row = im * 16 + fr;
            afc[im] = *(const h8v*)&Ah[row * 256 + ((kg0 + kgl) ^ (row & 7)) * 8];
        }
#pragma unroll
        for (int e = 0; e < 8; ++e) {
            const int set = e & 1;        // compile-time after unroll
            h8v as[4];
#pragma unroll
            for (int im = 0; im < 4; ++im) {
                _Float16 ah = (_Float16)areg[im][e];
                as[im] = afc[im] * ah;    // v_pk_mul_f16
            }
            __builtin_amdgcn_s_setprio(1);
#pragma unroll
            for (int im = 0; im < 4; ++im)
#pragma unroll
                for (int in = 0; in < 4; ++in)
                    acc[im][in] = __builtin_amdgcn_mfma_f32_16x16x32_f16(
                        as[im], bfs[set][in], acc[im][in], 0, 0, 0);
            __builtin_amdgcn_s_setprio(0);
            // prefetch step s = ki*8 + e + 2 into the set just consumed
            int ne, nki;
            if (e < 6) { ne = e + 2; nki = ki; }
            else       { ne = e - 6; nki = ki + 1; }
            if (nki > 7) { nki = 7; ne = 7; }   // clamp: harmless reload of last tile
            const ushort* tp = Wslice + (size_t)(ne * 8 + nki) * 8192;
#pragma unroll
            for (int in = 0; in < 4; ++in)
                bfs[set][in] = *(const h8v*)(tp + in * 512);
        }
    }

    // ---- epilogue: + sum_k alpha[b,k]*bias[k,o], optional relu, f32 store ----
    float bv[4][8];
#pragma unroll
    for (int in = 0; in < 4; ++in) {
        int col = wcol0 + in * 16 + fr;
#pragma unroll
        for (int k = 0; k < 8; ++k) bv[in][k] = bias[k * 256 + col];
    }
#pragma unroll
    for (int im = 0; im < 4; ++im) {
#pragma unroll
        for (int j = 0; j < 4; ++j) {
            int row = m0 + im * 16 + kgl * 4 + j;
            const float4* ap = (const float4*)(alpha + (size_t)row * 8);
            float4 a0 = ap[0], a1 = ap[1];
            float a8[8] = {a0.x, a0.y, a0.z, a0.w, a1.x, a1.y, a1.z, a1.w};
#pragma unroll
            for (int in = 0; in < 4; ++in) {
                int col = wcol0 + in * 16 + fr;
                float be = 0.f;
#pragma unroll
                for (int k = 0; k < 8; ++k) be = fmaf(a8[k], bv[in][k], be);
                float v = acc[im][in][j] + be;
                if (RELU) v = fmaxf(v, 0.f);
                Hout[(size_t)row * 256 + col] = v;
            }
        }
    }
}

extern "C" void kernel_launch(void* const* d_in, const int* in_sizes, int n_in,
                              void* d_out, int out_size, void* d_ws, size_t ws_size,
                              hipStream_t stream)
{
    const float* x      = (const float*)d_in[0];
    const float* gW     = (const float*)d_in[1];
    const float* gb     = (const float*)d_in[2];
    const float* blockW = (const float*)d_in[3];
    const float* blockB = (const float*)d_in[4];
    const float* outW   = (const float*)d_in[5];
    const float* outB   = (const float*)d_in[6];
    float* out = (float*)d_out;

    char* ws = (char*)d_ws;
    float*  alpha = (float*)ws;                 // 32768*8*4 = 1 MB
    ushort* Wg    = (ushort*)(ws + (1 << 20));  // 40*65536*2B = 5.25 MB

    prep_weights<<<320, 256, 0, stream>>>(blockW, outW, Wg);
    gate_kernel<<<8192, 256, 0, stream>>>(x, gW, gb, alpha);

    const size_t WL = (size_t)524288;   // ushorts per layer (8 experts x 8 g x 8192)
    moie_gemm<true ><<<512, 256, 0, stream>>>(x,   out, Wg,          blockB,            alpha);
    moie_gemm<true ><<<512, 256, 0, stream>>>(out, out, Wg + 1 * WL, blockB + 1 * 2048, alpha);
    moie_gemm<true ><<<512, 256, 0, stream>>>(out, out, Wg + 2 * WL, blockB + 2 * 2048, alpha);
    moie_gemm<true ><<<512, 256, 0, stream>>>(out, out, Wg + 3 * WL, blockB + 3 * 2048, alpha);
    moie_gemm<false><<<512, 256, 0, stream>>>(out, out, Wg + 4 * WL, outB,              alpha);
}